// Round 4
// baseline (797.312 us; speedup 1.0000x reference)
//
#include <hip/hip_runtime.h>
#include <math.h>

#define VOCAB 32000
#define NV4   (VOCAB / 4)     // 8000 float4 per token row
#define SEQ   2048
#define IGNORE_IDX (-100)
#define BS    256             // one block = one token

// Online-softmax state: m = running max, s = sum exp(x-m), t = sum exp(x-m)*(x-m)
// Branchless merge; deltas clamped so (-inf)*0 never produces NaN.
__device__ inline void merge_state(float& m, float& s, float& t,
                                   float om, float os, float ot) {
    float mm = fmaxf(m, om);
    float da = fmaxf(m - mm, -64.0f);
    float db = fmaxf(om - mm, -64.0f);
    float ca = __expf(da);
    float cb = __expf(db);
    t = ca * (t + da * s) + cb * (ot + db * os);
    s = ca * s + cb * os;
    m = mm;
}

// MEASUREMENT ROUND: this kernel is launched TWICE (idempotent) so its duration
// becomes visible via dur_us subtraction, and (if ~330us) its counter row enters
// the rocprof top-5. Body is byte-identical to round 3.
__global__ __launch_bounds__(BS, 4)
void ce_metrics_kernel(const float* __restrict__ logits,
                       const int* __restrict__ labels,
                       float* __restrict__ out,   // [0]=loss, [1..N]=ce, [1+N..2N]=entropy, then 3 accs
                       float* __restrict__ ws,    // per-token rank (-1 = invalid)
                       int N)
{
    const int token = blockIdx.x;          // one 256-thread block per token
    const int tid   = threadIdx.x;
    if (token >= N) return;

    float* ce_out  = out + 1;
    float* ent_out = out + 1 + N;

    const int pos = token & (SEQ - 1);
    const int label = (pos < SEQ - 1) ? labels[token + 1] : IGNORE_IDX;

    if (label < 0) {
        // label is block-uniform: every thread returns, barriers below never reached
        if (tid == 0) { ce_out[token] = 0.0f; ent_out[token] = 0.0f; ws[token] = -1.0f; }
        return;
    }

    const float* __restrict__ row = logits + (size_t)token * VOCAB;
    const float xl = row[label];               // same addr across block -> broadcast
    const float4* __restrict__ row4 = (const float4*)row;
    const float4* __restrict__ p    = row4 + tid;

    float m = -3.402823466e38f, s = 0.0f, t = 0.0f;
    int cgt = 0;   // #{x > xl}
    int ceq = 0;   // #{x == xl with lower vocab index}  (top_k tiebreak)

    auto process1 = [&](float4 x4, int i4) {
        float m4 = fmaxf(fmaxf(x4.x, x4.y), fmaxf(x4.z, x4.w));
        if (__any(m4 > m)) {                   // wave-uniform branch; rare after warmup
            float nm = fmaxf(m, m4);
            float d1 = fmaxf(m - nm, -64.0f);  // clamp: first iter exp(-64)*0 = 0, no NaN
            float c  = __expf(d1);
            float cs = c * s;
            t = fmaf(d1, cs, c * t);
            s = cs;
            m = nm;
        }
        float dx = x4.x - m, dy = x4.y - m, dz = x4.z - m, dw = x4.w - m;
        float ex = __expf(dx), ey = __expf(dy), ez = __expf(dz), ew = __expf(dw);
        s += (ex + ey) + (ez + ew);            // carried dep on s: one add
        float ta = fmaf(ex, dx, ey * dy);      // tree-reduce t contribution
        float tb = fmaf(ez, dz, ew * dw);
        t += ta + tb;                          // carried dep on t: one add

        const int base = i4 << 2;
        cgt += (x4.x > xl) + (x4.y > xl) + (x4.z > xl) + (x4.w > xl);
        ceq += ((x4.x == xl) & (base     < label))
             + ((x4.y == xl) & (base + 1 < label))
             + ((x4.z == xl) & (base + 2 < label))
             + ((x4.w == xl) & (base + 3 < label));
    };

    // 31 full 256-wide columns (float4 idx 0..7935) as 4 bursts: 8+8+8+7,
    // double-buffered so the next burst is in flight during processing.
    float4 A[8], B[8];
    #pragma unroll
    for (int k = 0; k < 8; ++k) A[k] = p[k * BS];                 // burst 0: base 0
    #pragma unroll
    for (int k = 0; k < 8; ++k) B[k] = p[2048 + k * BS];          // burst 1 in flight
    #pragma unroll
    for (int k = 0; k < 8; ++k) process1(A[k], tid + k * BS);
    #pragma unroll
    for (int k = 0; k < 8; ++k) A[k] = p[4096 + k * BS];          // burst 2 in flight
    #pragma unroll
    for (int k = 0; k < 8; ++k) process1(B[k], tid + 2048 + k * BS);
    #pragma unroll
    for (int k = 0; k < 7; ++k) B[k] = p[6144 + k * BS];          // burst 3 in flight
    #pragma unroll
    for (int k = 0; k < 8; ++k) process1(A[k], tid + 4096 + k * BS);
    #pragma unroll
    for (int k = 0; k < 7; ++k) process1(B[k], tid + 6144 + k * BS);

    // tail: float4 idx 7936..7999, handled by wave 0
    if (tid < 64) {
        const int j = 7936 + tid;
        process1(row4[j], j);
    }

    // 64-lane butterfly reduction within each wave
    #pragma unroll
    for (int mask = 32; mask; mask >>= 1) {
        float om = __shfl_xor(m, mask);
        float os = __shfl_xor(s, mask);
        float ot = __shfl_xor(t, mask);
        cgt += __shfl_xor(cgt, mask);
        ceq += __shfl_xor(ceq, mask);
        merge_state(m, s, t, om, os, ot);
    }

    // cross-wave merge via tiny LDS table (4 waves)
    __shared__ float sm[4], ss[4], st[4];
    __shared__ int   scg[4], sce[4];
    const int wid = tid >> 6, lane = tid & 63;
    if (lane == 0) { sm[wid] = m; ss[wid] = s; st[wid] = t; scg[wid] = cgt; sce[wid] = ceq; }
    __syncthreads();
    if (tid == 0) {
        m = sm[0]; s = ss[0]; t = st[0];
        merge_state(m, s, t, sm[1], ss[1], st[1]);
        merge_state(m, s, t, sm[2], ss[2], st[2]);
        merge_state(m, s, t, sm[3], ss[3], st[3]);
        cgt = (scg[0] + scg[1]) + (scg[2] + scg[3]);
        ceq = (sce[0] + sce[1]) + (sce[2] + sce[3]);
        float logs = logf(s);
        ce_out[token]  = m + logs - xl;
        ent_out[token] = logs - t / s;
        ws[token] = (float)(cgt + ceq);        // rank; label in top-k iff rank < k
    }
}

__global__ __launch_bounds__(256)
void finalize_kernel(const float* __restrict__ ws,
                     float* __restrict__ out, int N)
{
    const float* ce = out + 1;
    float ce_sum = 0.f, nv = 0.f, h1 = 0.f, h5 = 0.f, h20 = 0.f;
    for (int i = threadIdx.x; i < N; i += 256) {
        float r = ws[i];
        if (r >= 0.f) {
            nv     += 1.f;
            ce_sum += ce[i];
            h1  += (r < 1.f)  ? 1.f : 0.f;
            h5  += (r < 5.f)  ? 1.f : 0.f;
            h20 += (r < 20.f) ? 1.f : 0.f;
        }
    }
    #pragma unroll
    for (int mask = 32; mask; mask >>= 1) {
        ce_sum += __shfl_xor(ce_sum, mask);
        nv     += __shfl_xor(nv, mask);
        h1     += __shfl_xor(h1, mask);
        h5     += __shfl_xor(h5, mask);
        h20    += __shfl_xor(h20, mask);
    }
    __shared__ float red[5][4];
    const int wid = threadIdx.x >> 6, lane = threadIdx.x & 63;
    if (lane == 0) {
        red[0][wid] = ce_sum; red[1][wid] = nv;
        red[2][wid] = h1; red[3][wid] = h5; red[4][wid] = h20;
    }
    __syncthreads();
    if (threadIdx.x == 0) {
        ce_sum = red[0][0] + red[0][1] + red[0][2] + red[0][3];
        nv     = red[1][0] + red[1][1] + red[1][2] + red[1][3];
        h1     = red[2][0] + red[2][1] + red[2][2] + red[2][3];
        h5     = red[3][0] + red[3][1] + red[3][2] + red[3][3];
        h20    = red[4][0] + red[4][1] + red[4][2] + red[4][3];
        out[0]           = ce_sum / nv;
        out[1 + 2*N]     = h1  / nv;
        out[1 + 2*N + 1] = h5  / nv;
        out[1 + 2*N + 2] = h20 / nv;
    }
}

extern "C" void kernel_launch(void* const* d_in, const int* in_sizes, int n_in,
                              void* d_out, int out_size, void* d_ws, size_t ws_size,
                              hipStream_t stream) {
    const float* logits = (const float*)d_in[0];
    const int*   labels = (const int*)d_in[1];
    float* out = (float*)d_out;
    float* ws  = (float*)d_ws;

    const int N = in_sizes[1];   // B*S tokens (4096)

    // MEASUREMENT: double-launch (idempotent). dur_us delta vs round 3 (675us)
    // = one ce_metrics duration. If >=~325us, ce's counter row enters top-5.
    ce_metrics_kernel<<<N, BS, 0, stream>>>(logits, labels, out, ws, N);
    ce_metrics_kernel<<<N, BS, 0, stream>>>(logits, labels, out, ws, N);
    finalize_kernel<<<1, 256, 0, stream>>>(ws, out, N);
}

// Round 5
// 643.304 us; speedup vs baseline: 1.2394x; 1.2394x over previous
//
#include <hip/hip_runtime.h>
#include <math.h>

#define VOCAB 32000
#define NV4   (VOCAB / 4)     // 8000 float4 per token row
#define SEQ   2048
#define IGNORE_IDX (-100)
#define BS    256             // one block = one token

typedef float f32x4 __attribute__((ext_vector_type(4)));

// Online-softmax state: m = running max, s = sum exp(x-m), t = sum exp(x-m)*(x-m)
// Branchless merge; deltas clamped so (-inf)*0 never produces NaN.
__device__ inline void merge_state(float& m, float& s, float& t,
                                   float om, float os, float ot) {
    float mm = fmaxf(m, om);
    float da = fmaxf(m - mm, -64.0f);
    float db = fmaxf(om - mm, -64.0f);
    float ca = __expf(da);
    float cb = __expf(db);
    t = ca * (t + da * s) + cb * (ot + db * os);
    s = ca * s + cb * os;
    m = mm;
}

// Measured (round-4 double-launch subtraction): this kernel = 117 us = 4.5 TB/s,
// 71% of achievable read BW. This round: nontemporal loads (stream path, no L2
// thrash for a 524 MB read-once stream) + ballot/popcount rank counting (moves
// cgt/ceq from VALU adds to the co-issued scalar pipe; counts become wave-uniform).
__global__ __launch_bounds__(BS, 4)
void ce_metrics_kernel(const float* __restrict__ logits,
                       const int* __restrict__ labels,
                       float* __restrict__ out,   // [0]=loss, [1..N]=ce, [1+N..2N]=entropy, then 3 accs
                       float* __restrict__ ws,    // per-token rank (-1 = invalid)
                       int N)
{
    const int token = blockIdx.x;          // one 256-thread block per token
    const int tid   = threadIdx.x;
    if (token >= N) return;

    float* ce_out  = out + 1;
    float* ent_out = out + 1 + N;

    const int pos = token & (SEQ - 1);
    const int label = (pos < SEQ - 1) ? labels[token + 1] : IGNORE_IDX;

    if (label < 0) {
        // label is block-uniform: every thread returns, barriers below never reached
        if (tid == 0) { ce_out[token] = 0.0f; ent_out[token] = 0.0f; ws[token] = -1.0f; }
        return;
    }

    const float* __restrict__ row = logits + (size_t)token * VOCAB;
    const float xl = row[label];               // same addr across block -> broadcast
    const f32x4* __restrict__ row4 = (const f32x4*)row;
    const f32x4* __restrict__ p    = row4 + tid;

    float m = -3.402823466e38f, s = 0.0f, t = 0.0f;
    int cgt = 0;   // #{x > xl}            (wave-uniform: ballot-counted)
    int ceq = 0;   // #{x == xl, idx<label} (wave-uniform: ballot-counted)

    auto process1 = [&](f32x4 x4, int i4) {
        float m4 = fmaxf(fmaxf(x4.x, x4.y), fmaxf(x4.z, x4.w));
        if (__any(m4 > m)) {                   // wave-uniform branch; rare after warmup
            float nm = fmaxf(m, m4);
            float d1 = fmaxf(m - nm, -64.0f);  // clamp: first iter exp(-64)*0 = 0, no NaN
            float c  = __expf(d1);
            float cs = c * s;
            t = fmaf(d1, cs, c * t);
            s = cs;
            m = nm;
        }
        float dx = x4.x - m, dy = x4.y - m, dz = x4.z - m, dw = x4.w - m;
        float ex = __expf(dx), ey = __expf(dy), ez = __expf(dz), ew = __expf(dw);
        s += (ex + ey) + (ez + ew);            // carried dep on s: one add
        float ta = fmaf(ex, dx, ey * dy);      // tree-reduce t contribution
        float tb = fmaf(ez, dz, ew * dw);
        t += ta + tb;                          // carried dep on t: one add

        // rank counts: v_cmp -> ballot mask -> scalar popcount (co-issued with VALU)
        const int base = i4 << 2;
        cgt += __popcll(__ballot(x4.x > xl));
        cgt += __popcll(__ballot(x4.y > xl));
        cgt += __popcll(__ballot(x4.z > xl));
        cgt += __popcll(__ballot(x4.w > xl));
        ceq += __popcll(__ballot((x4.x == xl) & (base     < label)));
        ceq += __popcll(__ballot((x4.y == xl) & (base + 1 < label)));
        ceq += __popcll(__ballot((x4.z == xl) & (base + 2 < label)));
        ceq += __popcll(__ballot((x4.w == xl) & (base + 3 < label)));
    };

    // 31 full 256-wide columns (float4 idx 0..7935) as 4 bursts: 8+8+8+7,
    // double-buffered; nontemporal (streaming) loads bypass L2 allocation.
    f32x4 A[8], B[8];
    #pragma unroll
    for (int k = 0; k < 8; ++k) A[k] = __builtin_nontemporal_load(&p[k * BS]);
    #pragma unroll
    for (int k = 0; k < 8; ++k) B[k] = __builtin_nontemporal_load(&p[2048 + k * BS]);
    #pragma unroll
    for (int k = 0; k < 8; ++k) process1(A[k], tid + k * BS);
    #pragma unroll
    for (int k = 0; k < 8; ++k) A[k] = __builtin_nontemporal_load(&p[4096 + k * BS]);
    #pragma unroll
    for (int k = 0; k < 8; ++k) process1(B[k], tid + 2048 + k * BS);
    #pragma unroll
    for (int k = 0; k < 7; ++k) B[k] = __builtin_nontemporal_load(&p[6144 + k * BS]);
    #pragma unroll
    for (int k = 0; k < 8; ++k) process1(A[k], tid + 4096 + k * BS);
    #pragma unroll
    for (int k = 0; k < 7; ++k) process1(B[k], tid + 6144 + k * BS);

    // tail: float4 idx 7936..7999, handled by wave 0 (all 64 lanes active)
    if (tid < 64) {
        const int j = 7936 + tid;
        process1(__builtin_nontemporal_load(&row4[j]), j);
    }

    // 64-lane butterfly reduction within each wave (m/s/t only; counts are wave-uniform)
    #pragma unroll
    for (int mask = 32; mask; mask >>= 1) {
        float om = __shfl_xor(m, mask);
        float os = __shfl_xor(s, mask);
        float ot = __shfl_xor(t, mask);
        merge_state(m, s, t, om, os, ot);
    }

    // cross-wave merge via tiny LDS table (4 waves)
    __shared__ float sm[4], ss[4], st[4];
    __shared__ int   scg[4], sce[4];
    const int wid = tid >> 6, lane = tid & 63;
    if (lane == 0) { sm[wid] = m; ss[wid] = s; st[wid] = t; scg[wid] = cgt; sce[wid] = ceq; }
    __syncthreads();
    if (tid == 0) {
        m = sm[0]; s = ss[0]; t = st[0];
        merge_state(m, s, t, sm[1], ss[1], st[1]);
        merge_state(m, s, t, sm[2], ss[2], st[2]);
        merge_state(m, s, t, sm[3], ss[3], st[3]);
        cgt = (scg[0] + scg[1]) + (scg[2] + scg[3]);
        ceq = (sce[0] + sce[1]) + (sce[2] + sce[3]);
        float logs = logf(s);
        ce_out[token]  = m + logs - xl;
        ent_out[token] = logs - t / s;
        ws[token] = (float)(cgt + ceq);        // rank; label in top-k iff rank < k
    }
}

__global__ __launch_bounds__(256)
void finalize_kernel(const float* __restrict__ ws,
                     float* __restrict__ out, int N)
{
    const float* ce = out + 1;
    float ce_sum = 0.f, nv = 0.f, h1 = 0.f, h5 = 0.f, h20 = 0.f;
    for (int i = threadIdx.x; i < N; i += 256) {
        float r = ws[i];
        if (r >= 0.f) {
            nv     += 1.f;
            ce_sum += ce[i];
            h1  += (r < 1.f)  ? 1.f : 0.f;
            h5  += (r < 5.f)  ? 1.f : 0.f;
            h20 += (r < 20.f) ? 1.f : 0.f;
        }
    }
    #pragma unroll
    for (int mask = 32; mask; mask >>= 1) {
        ce_sum += __shfl_xor(ce_sum, mask);
        nv     += __shfl_xor(nv, mask);
        h1     += __shfl_xor(h1, mask);
        h5     += __shfl_xor(h5, mask);
        h20    += __shfl_xor(h20, mask);
    }
    __shared__ float red[5][4];
    const int wid = threadIdx.x >> 6, lane = threadIdx.x & 63;
    if (lane == 0) {
        red[0][wid] = ce_sum; red[1][wid] = nv;
        red[2][wid] = h1; red[3][wid] = h5; red[4][wid] = h20;
    }
    __syncthreads();
    if (threadIdx.x == 0) {
        ce_sum = red[0][0] + red[0][1] + red[0][2] + red[0][3];
        nv     = red[1][0] + red[1][1] + red[1][2] + red[1][3];
        h1     = red[2][0] + red[2][1] + red[2][2] + red[2][3];
        h5     = red[3][0] + red[3][1] + red[3][2] + red[3][3];
        h20    = red[4][0] + red[4][1] + red[4][2] + red[4][3];
        out[0]           = ce_sum / nv;
        out[1 + 2*N]     = h1  / nv;
        out[1 + 2*N + 1] = h5  / nv;
        out[1 + 2*N + 2] = h20 / nv;
    }
}

extern "C" void kernel_launch(void* const* d_in, const int* in_sizes, int n_in,
                              void* d_out, int out_size, void* d_ws, size_t ws_size,
                              hipStream_t stream) {
    const float* logits = (const float*)d_in[0];
    const int*   labels = (const int*)d_in[1];
    float* out = (float*)d_out;
    float* ws  = (float*)d_ws;

    const int N = in_sizes[1];   // B*S tokens (4096)

    ce_metrics_kernel<<<N, BS, 0, stream>>>(logits, labels, out, ws, N);
    finalize_kernel<<<1, 256, 0, stream>>>(ws, out, N);
}